// Round 18
// baseline (403.876 us; speedup 1.0000x reference)
//
#include <hip/hip_runtime.h>
#include <hip/hip_bf16.h>

// Model_3315714753203: B=4,S=2048,I=512,D=512,H=8,HD=64,P=720.
// SINGLE persistent kernel (plain launch, 512 blocks; all co-resident by
// construction: LDS 32.8KB -> 4/CU, launch_bounds(256,2) -> VGPR<=256 ->
// 2/CU, capacity 512 = grid). Phases separated by a SOFTWARE grid barrier
// (device-scope atomics + fences; one-shot counters zeroed via
// hipMemsetAsync). r17's hipLaunchCooperativeKernel was silently rejected
// (all-zeros output); this has no rejectable launch path.
// Phases: convert -> qkv -> flash -> up -> out (all r16-verified bodies).

typedef short bf16x8 __attribute__((ext_vector_type(8)));
typedef short short4v __attribute__((ext_vector_type(4)));
typedef float f32x4 __attribute__((ext_vector_type(4)));
typedef const __attribute__((address_space(1))) void* gptr_t;
typedef __attribute__((address_space(3))) void* sptr_t;

__device__ __forceinline__ f32x4 mfma16(bf16x8 a, bf16x8 b, f32x4 c) {
    return __builtin_amdgcn_mfma_f32_16x16x32_bf16(a, b, c, 0, 0, 0);
}
__device__ __forceinline__ f32x4 mfma16k(short4v a, short4v b, f32x4 c) {
#if __has_builtin(__builtin_amdgcn_mfma_f32_16x16x16bf16_1k)
    return __builtin_amdgcn_mfma_f32_16x16x16bf16_1k(a, b, c, 0, 0, 0);
#else
    (void)a; (void)b; return c;   // host-pass stub
#endif
}
__device__ __forceinline__ void async16(const void* g, void* l) {
    __builtin_amdgcn_global_load_lds((gptr_t)g, (sptr_t)l, 16, 0, 0);
}
__device__ __forceinline__ float fexp2(float x) {
#if __has_builtin(__builtin_amdgcn_exp2f)
    return __builtin_amdgcn_exp2f(x);
#else
    return exp2f(x);
#endif
}
// pack 4 f32 -> 4 bf16 (round-half-up) — FLASH ONLY (HW-verified there).
__device__ __forceinline__ short4v pack_bf16x4(f32x4 v) {
    unsigned a = __builtin_bit_cast(unsigned, v[0]) + 0x8000u;
    unsigned b = __builtin_bit_cast(unsigned, v[1]) + 0x8000u;
    unsigned c = __builtin_bit_cast(unsigned, v[2]) + 0x8000u;
    unsigned d = __builtin_bit_cast(unsigned, v[3]) + 0x8000u;
    int2 t;
    t.x = (int)__builtin_amdgcn_perm(b, a, 0x07060302u);
    t.y = (int)__builtin_amdgcn_perm(d, c, 0x07060302u);
    return __builtin_bit_cast(short4v, t);
}

// ---- software grid barrier: one-shot counter per phase boundary.
// Release: threadfence (agent) + atomicAdd (device-scope, m20).
// Acquire: device-scope RMW spin + threadfence (invalidates L1/L2 shard).
// Bounded spin -> wrong-but-diagnosable instead of harness timeout.
__device__ __forceinline__ void gbar(unsigned* cnt, unsigned nb) {
    __syncthreads();
    if (threadIdx.x == 0) {
        __threadfence();
        atomicAdd(cnt, 1u);
        long long t0 = clock64();
        while (atomicAdd(cnt, 0u) < nb) {
            __builtin_amdgcn_s_sleep(2);
            if (clock64() - t0 > (3LL << 30)) break;   // ~1.3s safety valve
        }
        __threadfence();
    }
    __syncthreads();
}

// ---------------- generalized GEMM body: C[tile] = A[M,K]*B[N,K]^T (+biases)*csc
// lda == ldb == K at every call site. XOR-chunk-swizzled LDS (r13-verified).
template<int BM, int BN>
__device__ __forceinline__ void gemm_body(
    const __hip_bfloat16* __restrict__ A,
    const __hip_bfloat16* __restrict__ B,
    void* __restrict__ C,
    int M, int N, int K, int m0, int n0, int ldc,
    const __hip_bfloat16* biasM, const __hip_bfloat16* biasN,
    float csc, int outF32,
    __hip_bfloat16* lA, __hip_bfloat16* lB)
{
    constexpr int FM = BM / 32, FN = BN / 32;
    const int tid = threadIdx.x, lane = tid & 63, wave = tid >> 6;
    const int wm = (wave >> 1) * (BM / 2), wn = (wave & 1) * (BN / 2);
    const int lc = lane & 15, lg = lane >> 4;

    f32x4 acc[FM][FN] = {};
    constexpr int CA = BM * 8 / 256, CB = BN * 8 / 256;

    for (int k0 = 0; k0 < K; k0 += 64) {
        #pragma unroll
        for (int j = 0; j < CA; ++j) {
            int ch = j * 256 + tid;
            int m = ch >> 3, kc = (ch & 7) ^ (m & 7);
            int mg = m0 + m; if (mg > M - 1) mg = M - 1;
            async16(&A[(size_t)mg * K + k0 + kc * 8], &lA[ch * 8]);
        }
        #pragma unroll
        for (int j = 0; j < CB; ++j) {
            int ch = j * 256 + tid;
            int n = ch >> 3, kc = (ch & 7) ^ (n & 7);
            int ng = n0 + n; if (ng > N - 1) ng = N - 1;
            async16(&B[(size_t)ng * K + k0 + kc * 8], &lB[ch * 8]);
        }
        __syncthreads();
        #pragma unroll
        for (int ks = 0; ks < 64; ks += 32) {
            bf16x8 af[FM], bfr[FN];
            #pragma unroll
            for (int i = 0; i < FM; ++i) {
                int row = wm + i * 16 + lc;
                af[i] = *(const bf16x8*)&lA[row * 64 + (((ks >> 3) + lg) ^ (row & 7)) * 8];
            }
            #pragma unroll
            for (int j = 0; j < FN; ++j) {
                int row = wn + j * 16 + lc;
                bfr[j] = *(const bf16x8*)&lB[row * 64 + (((ks >> 3) + lg) ^ (row & 7)) * 8];
            }
            #pragma unroll
            for (int i = 0; i < FM; ++i)
                #pragma unroll
                for (int j = 0; j < FN; ++j)
                    acc[i][j] = mfma16(af[i], bfr[j], acc[i][j]);
        }
        __syncthreads();
    }
    #pragma unroll
    for (int i = 0; i < FM; ++i) {
        int rbase = m0 + wm + i * 16 + lg * 4;
        #pragma unroll
        for (int j = 0; j < FN; ++j) {
            int col = n0 + wn + j * 16 + lc;
            if (col >= N) continue;
            float bn = biasN ? (float)biasN[col] : 0.0f;
            #pragma unroll
            for (int r = 0; r < 4; ++r) {
                int row = rbase + r;
                if (row < M) {
                    float v = acc[i][j][r] + bn;
                    if (biasM) v += (float)biasM[row];
                    v *= csc;
                    size_t idx = (size_t)row * ldc + col;
                    if (outF32) ((float*)C)[idx] = v;
                    else ((__hip_bfloat16*)C)[idx] = __float2bfloat16(v);
                }
            }
        }
    }
}

// ---------------- flash body (r16-verified v8)
__device__ __forceinline__ void flash_body(
    const __hip_bfloat16* __restrict__ q,
    const __hip_bfloat16* __restrict__ k,
    const __hip_bfloat16* __restrict__ vT,
    __hip_bfloat16* __restrict__ cT,
    int bx, int by, __hip_bfloat16* smem)
{
    const int S = 2048;
    const int h = by >> 2, b = by & 3;
    const int tid = threadIdx.x, lane = tid & 63, wave = tid >> 6;
    const int lc = lane & 15, lg = lane >> 4;
    const int s0 = bx * 128 + wave * 32;

    const __hip_bfloat16* qb = q  + (size_t)(h * 4 + b) * S * 64;
    const __hip_bfloat16* kb = k  + (size_t)(h * 4 + b) * S * 64;
    const __hip_bfloat16* vb = vT + (size_t)(h * 4 + b) * 64 * S;

    __hip_bfloat16* lk = smem;
    __hip_bfloat16* lv = smem + 8192;

    bf16x8 qf[2][2];
    #pragma unroll
    for (int f = 0; f < 2; ++f)
        #pragma unroll
        for (int hh = 0; hh < 2; ++hh)
            qf[f][hh] = *(const bf16x8*)&qb[(size_t)(s0 + f * 16 + lc) * 64 + hh * 32 + lg * 8];

    int koff[4][2], voff[4][4];
    const int half8 = (lg & 1) * 4;
    #pragma unroll
    for (int kg = 0; kg < 4; ++kg) {
        int row = kg * 16 + lc, sw = row & 7;
        koff[kg][0] = row * 64 + ((0 + lg) ^ sw) * 8;
        koff[kg][1] = row * 64 + ((4 + lg) ^ sw) * 8;
    }
    #pragma unroll
    for (int dt = 0; dt < 4; ++dt) {
        int row = dt * 16 + lc, sw = row & 7;
        #pragma unroll
        for (int kg = 0; kg < 4; ++kg)
            voff[dt][kg] = row * 64 + ((2 * kg + (lg >> 1)) ^ sw) * 8 + half8;
    }
    int sld[2], skg[2]; size_t svg[2];
    #pragma unroll
    for (int j = 0; j < 2; ++j) {
        int ch = j * 256 + tid;
        int row = ch >> 3, cg = (ch & 7) ^ (row & 7);
        sld[j] = ch * 8;
        skg[j] = row * 64 + cg * 8;
        svg[j] = (size_t)row * S + cg * 8;
    }

    #pragma unroll
    for (int j = 0; j < 2; ++j) {
        async16(&kb[skg[j]], &lk[sld[j]]);
        async16(&vb[svg[j]], &lv[sld[j]]);
    }
    __syncthreads();

    f32x4 O[2][4] = {};
    f32x4 lsum[2] = {};

    auto step = [&](int tn, int cur, int nxt) {
        if (tn + 1 < 32) {
            const int t1 = (tn + 1) * 64;
            #pragma unroll
            for (int j = 0; j < 2; ++j) {
                async16(&kb[(size_t)t1 * 64 + skg[j]], &lk[nxt + sld[j]]);
                async16(&vb[svg[j] + t1],              &lv[nxt + sld[j]]);
            }
        }
        f32x4 sc[2][4] = {};
        #pragma unroll
        for (int kg = 0; kg < 4; ++kg) {
            bf16x8 kf0 = *(const bf16x8*)&lk[cur + koff[kg][0]];
            bf16x8 kf1 = *(const bf16x8*)&lk[cur + koff[kg][1]];
            #pragma unroll
            for (int f = 0; f < 2; ++f) {
                sc[f][kg] = mfma16(kf0, qf[f][0], sc[f][kg]);
                sc[f][kg] = mfma16(kf1, qf[f][1], sc[f][kg]);
            }
        }
        short4v pb[2][4];
        #pragma unroll
        for (int f = 0; f < 2; ++f)
            #pragma unroll
            for (int kg = 0; kg < 4; ++kg) {
                f32x4 e;
                #pragma unroll
                for (int r = 0; r < 4; ++r) e[r] = fexp2(sc[f][kg][r]);
                lsum[f] += e;
                pb[f][kg] = pack_bf16x4(e);
            }
        #pragma unroll
        for (int dt = 0; dt < 4; ++dt)
            #pragma unroll
            for (int kg = 0; kg < 4; ++kg) {
                short4v vf = *(const short4v*)&lv[cur + voff[dt][kg]];
                O[0][dt] = mfma16k(vf, pb[0][kg], O[0][dt]);
                O[1][dt] = mfma16k(vf, pb[1][kg], O[1][dt]);
            }
        __syncthreads();
    };

    for (int t = 0; t < 32; t += 2) {
        step(t, 0, 4096);
        step(t + 1, 4096, 0);
    }

    float inv[2];
    #pragma unroll
    for (int f = 0; f < 2; ++f) {
        float v = lsum[f][0] + lsum[f][1] + lsum[f][2] + lsum[f][3];
        v += __shfl_xor(v, 16);
        v += __shfl_xor(v, 32);
        inv[f] = 1.0f / v;
    }
    #pragma unroll
    for (int f = 0; f < 2; ++f)
        #pragma unroll
        for (int dt = 0; dt < 4; ++dt)
            #pragma unroll
            for (int r = 0; r < 4; ++r)
                smem[(dt * 16 + lg * 4 + r) * 136 + wave * 32 + f * 16 + lc] =
                    __float2bfloat16(O[f][dt][r] * inv[f]);
    __syncthreads();
    int row = tid >> 2, c0 = (tid & 3) * 32;
    size_t off = ((size_t)b * 512 + h * 64 + row) * S + bx * 128 + c0;
    #pragma unroll
    for (int cc = 0; cc < 4; ++cc)
        *(bf16x8*)&cT[off + cc * 8] = *(const bf16x8*)&smem[row * 136 + c0 + cc * 8];
}

// ---------------- fused persistent kernel (plain launch + software barriers)
struct Params {
    const void* in[11];
    void* out;
    __hip_bfloat16* ws;
    unsigned* cnt;   // 4 one-shot barrier counters (memset to 0 pre-launch)
};

__global__ __launch_bounds__(256, 2) void fused_all(Params p) {
    __shared__ __align__(16) __hip_bfloat16 smem[16384];
    __shared__ int sflag;

    using bf = __hip_bfloat16;
    bf* ws  = p.ws;
    bf* bqc = ws + 64;       // bqc/bkc contiguous
    bf* bvc = ws + 1088;
    bf* btc = ws + 1600;
    bf* boc = ws + 2320;
    bf* WqT = ws + 4096;     // WqT/WkT contiguous
    bf* WkT = ws + 266240;
    bf* WvT = ws + 528384;
    bf* Wtc = ws + 790528;
    bf* Woc = ws + 2265088;
    bf* Xc  = ws + 2527232;  // dead after qkv
    bf* cT  = ws + 2527232;  // overlays Xc (written in flash phase)
    bf* q   = ws + 6721536;  // dead after flash
    bf* up  = ws + 6721536;  // overlays q (written in up phase)
    bf* kk  = ws + 10915840;
    bf* vT  = ws + 15110144;
    bf* bkc = ws + 576;

    const int bid = blockIdx.x;   // 0..511
    const int tid = threadIdx.x;
    const unsigned NB = 512;

    // dtype probe (per-block, register-resident)
    if (tid < 64) {
        unsigned e = (((const unsigned*)p.in[0])[tid] >> 23) & 0xffu;
        unsigned long long m = __ballot(e >= 100u && e <= 145u);
        if (tid == 0) sflag = (__popcll(m) >= 32) ? 1 : 0;
    }
    __syncthreads();
    const int isF32 = sflag;

    // ---- phase 0: convert (r16-verified semantics)
    {
        const void* srcs[11] = { p.in[0], p.in[1], p.in[2], p.in[3], p.in[4],
                                 p.in[5], p.in[6], p.in[7], p.in[8], p.in[9], p.in[10] };
        bf* dsts[11] = { Xc, WqT, bqc, WkT, bkc, WvT, bvc, Wtc, btc, Woc, boc };
        const int ns[11]  = { 4194304, 262144, 512, 262144, 512, 262144, 512,
                              1474560, 720, 262144, 512 };
        const int mds[11] = { 0, 1, 0, 1, 0, 1, 0, 0, 0, 0, 0 };
        for (int t = 0; t < 11; ++t) {
            const int n = ns[t];
            bf* d = dsts[t];
            if (mds[t] == 0 && isF32) {
                const int n4 = n >> 2;
                for (int i4 = bid * 256 + tid; i4 < n4; i4 += 512 * 256) {
                    float4 f = ((const float4*)srcs[t])[i4];
                    bf* dd = d + i4 * 4;
                    dd[0] = __float2bfloat16(f.x);
                    dd[1] = __float2bfloat16(f.y);
                    dd[2] = __float2bfloat16(f.z);
                    dd[3] = __float2bfloat16(f.w);
                }
            } else {
                for (int i = bid * 256 + tid; i < n; i += 512 * 256) {
                    int si = i;
                    if (mds[t]) {
                        int ii = i & 511, dd = (i >> 9) & 63, h = i >> 15;
                        si = (h * 512 + ii) * 64 + dd;
                    }
                    float v = isF32 ? ((const float*)srcs[t])[si]
                                    : (float)((const bf*)srcs[t])[si];
                    d[i] = __float2bfloat16(v);
                }
            }
        }
    }
    gbar(p.cnt + 0, NB);

    // ---- phase 1: qkv projections (1536 jobs; r13/r16-verified shapes)
    const float qscale = 0.022542110013890054f;  // log2(e)/64
    for (int j = bid; j < 1536; j += 512) {
        if (j < 1024) {
            int z1 = j >> 6, yt = j & 63;
            gemm_body<128, 64>(
                Xc, WqT + z1 * 32768, q + (size_t)z1 * 524288,
                8192, 64, 512, yt * 128, 0, 64,
                nullptr, bqc + z1 * 64, (z1 < 8) ? qscale : 1.0f, 0,
                smem, smem + 8192);
        } else {
            int t = j - 1024, z = t >> 4, xt = t & 15;
            int h = z >> 2, b = z & 3;
            gemm_body<64, 128>(
                WvT + h * 32768, Xc + (size_t)b * 1048576,
                vT + (size_t)h * 524288 + b * 131072,
                64, 2048, 512, 0, xt * 128, 2048,
                bvc + h * 64, nullptr, 1.0f, 0,
                smem, smem + 4096);
        }
    }
    gbar(p.cnt + 1, NB);

    // ---- phase 2: flash attention (512 jobs; r16 grid (16,32))
    for (int j = bid; j < 512; j += 512)
        flash_body(q, kk, vT, cT, j & 15, j >> 4, smem);
    gbar(p.cnt + 2, NB);

    // ---- phase 3: up GEMM (384 jobs; r16 grid (8,12,4))
    for (int j = bid; j < 384; j += 512) {
        int b = j / 96, rem = j - b * 96, yt = rem >> 3, xt = rem & 7;
        gemm_body<64, 64>(
            Wtc, cT + (size_t)b * 1048576, up + (size_t)b * 368640,
            720, 512, 2048, yt * 64, xt * 64, 512,
            btc, nullptr, 1.0f, 0,
            smem, smem + 4096);
    }
    gbar(p.cnt + 3, NB);

    // ---- phase 4: out GEMM (360 jobs; r16 grid (8,45)); dtype per probe
    for (int j = bid; j < 360; j += 512) {
        int yt = j >> 3, xt = j & 7;
        gemm_body<64, 64>(
            up, Woc, p.out,
            2880, 512, 512, yt * 64, xt * 64, 512,
            nullptr, boc, 1.0f, isF32,
            smem, smem + 4096);
    }
}

extern "C" void kernel_launch(void* const* d_in, const int* in_sizes, int n_in,
                              void* d_out, int out_size, void* d_ws, size_t ws_size,
                              hipStream_t stream) {
    Params prm;
    for (int i = 0; i < 11; ++i) prm.in[i] = d_in[i];
    prm.out = d_out;
    prm.ws = (__hip_bfloat16*)d_ws;
    // barrier counters: past the 38.6MB layout, inside the 46.5MB region
    // proven writable in r1/r2; zeroed every call (capture-legal memset).
    prm.cnt = (unsigned*)((char*)d_ws + 38701056);
    hipMemsetAsync(prm.cnt, 0, 64, stream);
    fused_all<<<dim3(512), dim3(256), 0, stream>>>(prm);
}